// Round 2
// baseline (374.973 us; speedup 1.0000x reference)
//
#include <hip/hip_runtime.h>
#include <math.h>

#define DIM 512
#define KCB 1024
#define BM  64
// ws layout (bytes)
#define CBT_OFF   0u         // CB fp16 pre-swizzled: [2 halves][16 chunks of 32 d][32KB] = 1 MB
#define CNORM_OFF 1048576u   // 4 KB
#define XNORM_OFF 1052672u   // 256 KB
#define HIST_OFF  1314816u   // 4 KB
#define LOSS_OFF  1318912u   // 64 B
#define XO 16                // X fp16 region offset inside d_out (block-owned slabs)

typedef _Float16 half8 __attribute__((ext_vector_type(8)));
typedef float floatx4 __attribute__((ext_vector_type(4)));

// async global->LDS DMA, 16B/lane; LDS dest = wave-uniform base + lane*16
__device__ __forceinline__ void g2l16(const void* g, void* l) {
    __builtin_amdgcn_global_load_lds(
        (const __attribute__((address_space(1))) unsigned int*)g,
        (__attribute__((address_space(3))) unsigned int*)l, 16, 0, 0);
}

__device__ __forceinline__ half8 cvt8(float4 a, float4 b) {
    half8 h;
    h[0] = (_Float16)a.x; h[1] = (_Float16)a.y; h[2] = (_Float16)a.z; h[3] = (_Float16)a.w;
    h[4] = (_Float16)b.x; h[5] = (_Float16)b.y; h[6] = (_Float16)b.z; h[7] = (_Float16)b.w;
    return h;
}
__device__ __forceinline__ float sq8(float4 a, float4 b) {
    return a.x*a.x + a.y*a.y + a.z*a.z + a.w*a.w
         + b.x*b.x + b.y*b.y + b.z*b.z + b.w*b.w;
}

// 32-d chunk image layout: granule = 8 halves (16B) of (row r, q-group q in 0..3).
// line = r>>1 (128B line = 2 rows), slot = ((r&1)*4 + q) ^ (line&7).
// Any aligned 8-lane octet of a ds_read_b128 (fixed q, 8 consecutive ln) hits 8
// distinct bank-quads: quad = (b*4+q)^m with b spanning {0,1}, m spanning one
// bit2-half -> bijective. Linear slot order = DMA-compatible (rule #21).

// ---------------- merged prep: X->fp16 swizzled + xnorm | CB->fp16 swizzled + cnorm ----------------
__global__ __launch_bounds__(256) void prep(const float* __restrict__ X,
                                            const float* __restrict__ CB,
                                            char* __restrict__ ob,
                                            char* __restrict__ ws) {
    const int t = threadIdx.x;
    const int w = t >> 6, lane = t & 63;
    const int dc = lane >> 2, q = lane & 3;  // lane covers d = dc*32 + q*8 .. +7 = lane*8..+7
    const int b = blockIdx.x;
    if (b < 2048) {
        // X: 32 rows per block, 8 per wave
        for (int it = 0; it < 8; ++it) {
            int r = b * 32 + w * 8 + it;
            const float4* src = (const float4*)(X + (size_t)r * DIM);
            float4 v0 = src[lane * 2];
            float4 v1 = src[lane * 2 + 1];
            int rl = r & 63;
            int line = rl >> 1;
            int sl = ((((rl & 1) << 2) | q) ^ (line & 7));
            *(half8*)(ob + XO + (size_t)(r >> 6) * 131072 + dc * 4096
                      + (line * 8 + sl) * 16) = cvt8(v0, v1);
            float s = sq8(v0, v1);
#pragma unroll
            for (int off = 32; off > 0; off >>= 1) s += __shfl_xor(s, off);
            if (lane == 0) ((float*)(ws + XNORM_OFF))[r] = s;
        }
    } else {
        int k = (b - 2048) * 4 + w;  // one code per wave
        const float4* src = (const float4*)(CB + (size_t)k * DIM);
        float4 v0 = src[lane * 2];
        float4 v1 = src[lane * 2 + 1];
        int kl = k & 511;
        int line = kl >> 1;
        int sl = ((((kl & 1) << 2) | q) ^ (line & 7));
        *(half8*)(ws + CBT_OFF + (size_t)(k >> 9) * 524288 + dc * 32768
                  + (line * 8 + sl) * 16) = cvt8(v0, v1);
        float s = sq8(v0, v1);
#pragma unroll
        for (int off = 32; off > 0; off >>= 1) s += __shfl_xor(s, off);
        if (lane == 0) ((float*)(ws + CNORM_OFF))[k] = s;
    }
}

// ---------------- main: pipelined fp16 MFMA scores + fused argmin/epilogue ----------------
__global__ __launch_bounds__(256, 2) void vq_main(
    char* __restrict__ ob, const float* __restrict__ CB32,
    const char* __restrict__ ws, int* __restrict__ hist,
    float* __restrict__ loss_acc) {
    extern __shared__ char smem[];
    // CBb0 @0 (32KB), CBb1 @32768 (32KB), Xb0 @65536 (4KB), Xb1 @69632 (4KB) = 73728
    // epilogue overlay (after final sync):
    float* argS = (float*)smem;           // [4][64]
    int*   argI = (int*)(smem + 1024);    // [4][64]
    int*   idxF = (int*)(smem + 2048);    // [64]

    const int t = threadIdx.x;
    const int lane = t & 63;
    const int wu = __builtin_amdgcn_readfirstlane(t >> 6);  // wave id (scalar)
    const int ln = lane & 15, q = lane >> 4;
    const int rb = blockIdx.x;
    const int rowbase = rb * BM;
    const float* cnorm = (const float*)(ws + CNORM_OFF);
    const float* xnorm = (const float*)(ws + XNORM_OFF);

    // shared read offset within a 1KB (16-row) sub-block, conflict-free swizzle
    const int xoff = (ln >> 1) * 128 + (((((ln & 1) << 2) | q) ^ (ln >> 1)) << 4);

    const char* cbase = ws + CBT_OFF;
    const char* xbase = ob + XO + (size_t)rb * 131072;

    float bestS[16];
    int bestI[16];
#pragma unroll
    for (int li = 0; li < 16; ++li) { bestS[li] = 3.0e38f; bestI[li] = 0; }

    // ---- prologue: stage step 0 (h=0, dc=0) into buffer 0 ----
    {
#pragma unroll
        for (int i = 0; i < 8; ++i) {
            int p = i * 4 + wu;
            g2l16(cbase + p * 1024 + lane * 16, smem + p * 1024);
        }
        g2l16(xbase + (wu * 64 + lane) * 16, smem + 65536 + wu * 1024);
    }
    __syncthreads();  // implicit vmcnt(0) drain: step-0 data ready

    for (int h = 0; h < 2; ++h) {
        floatx4 acc[4][8];
#pragma unroll
        for (int ar = 0; ar < 4; ++ar)
#pragma unroll
            for (int bc = 0; bc < 8; ++bc) acc[ar][bc] = (floatx4){0.f, 0.f, 0.f, 0.f};

#pragma unroll 2
        for (int dc = 0; dc < 16; ++dc) {
            const int cb = dc & 1;  // compile-time after unroll-2 (h*16 keeps parity)
            char* Cc = smem + cb * 32768;
            char* Xc = smem + 65536 + cb * 4096;
            const int s = h * 16 + dc;

            if (s < 31) {
                // issue next step's DMAs BEFORE compute (pipeline stage s+1 under compute s)
                const int s2 = s + 1;
                const char* csrc = cbase + (size_t)(s2 >> 4) * 524288 + (size_t)(s2 & 15) * 32768;
                char* Cn = smem + (cb ^ 1) * 32768;
#pragma unroll
                for (int i = 0; i < 8; ++i) {
                    int p = i * 4 + wu;
                    g2l16(csrc + p * 1024 + lane * 16, Cn + p * 1024);
                }
                g2l16(xbase + (size_t)(s2 & 15) * 4096 + (wu * 64 + lane) * 16,
                      smem + 65536 + (cb ^ 1) * 4096 + wu * 1024);
            }

            // compute current chunk (one K=32 MFMA step, 32 MFMAs)
            half8 a[4];
#pragma unroll
            for (int ar = 0; ar < 4; ++ar)
                a[ar] = *(const half8*)(Xc + ar * 1024 + xoff);
#pragma unroll
            for (int bc = 0; bc < 8; ++bc) {
                half8 bfr = *(const half8*)(Cc + wu * 8192 + bc * 1024 + xoff);
#pragma unroll
                for (int ar = 0; ar < 4; ++ar)
                    acc[ar][bc] = __builtin_amdgcn_mfma_f32_16x16x32_f16(a[ar], bfr, acc[ar][bc], 0, 0, 0);
            }
            __syncthreads();  // single drain per step: next-step DMAs complete
        }

        // fold this half (ascending cols -> strict < keeps first occurrence)
#pragma unroll
        for (int bc = 0; bc < 8; ++bc) {
            int col = h * 512 + wu * 128 + bc * 16 + ln;
            float cn = cnorm[col];
#pragma unroll
            for (int ar = 0; ar < 4; ++ar)
#pragma unroll
                for (int r = 0; r < 4; ++r) {
                    float sdist = fmaf(-2.f, acc[ar][bc][r], cn);
                    int li = ar * 4 + r;
                    if (sdist < bestS[li]) { bestS[li] = sdist; bestI[li] = col; }
                }
        }
    }

    // butterfly across the 16 ln-lanes (lowest index wins ties)
#pragma unroll
    for (int off = 1; off <= 8; off <<= 1) {
#pragma unroll
        for (int li = 0; li < 16; ++li) {
            float s2 = __shfl_xor(bestS[li], off);
            int i2 = __shfl_xor(bestI[li], off);
            if (s2 < bestS[li] || (s2 == bestS[li] && i2 < bestI[li])) {
                bestS[li] = s2; bestI[li] = i2;
            }
        }
    }
    __syncthreads();  // all LDS frag reads done before overlay writes
    if (ln == 0) {
#pragma unroll
        for (int li = 0; li < 16; ++li) {
            int row = (li >> 2) * 16 + q * 4 + (li & 3);
            argS[wu * 64 + row] = bestS[li];
            argI[wu * 64 + row] = bestI[li];
        }
    }
    __syncthreads();
    if (t < BM) {  // exactly wave 0
        float s = argS[t];
        int bi = argI[t];
#pragma unroll
        for (int ww = 1; ww < 4; ++ww) {
            float s2 = argS[ww * 64 + t];
            int i2 = argI[ww * 64 + t];
            if (s2 < s || (s2 == s && i2 < bi)) { s = s2; bi = i2; }
        }
        idxF[t] = bi;
        atomicAdd(&hist[bi], 1);
        float l = s + xnorm[rowbase + t];  // ||x - c_best||^2
#pragma unroll
        for (int off = 32; off > 0; off >>= 1) l += __shfl_xor(l, off);
        if (t == 0) atomicAdd(loss_acc, l);
    }
    __syncthreads();
    // gather + write quantized (overwrites this block's own X-fp16 slab only)
    float* outq = (float*)ob + 1;
    for (int m = 0; m < BM; ++m) {
        int bi = idxF[m];
        const float* crow = CB32 + (size_t)bi * DIM;
        float v0 = crow[t];
        float v1 = crow[t + 256];
        size_t base = (size_t)(rowbase + m) * DIM;
        outq[base + t] = v0;
        outq[base + t + 256] = v1;
    }
}

// ---------------- finalize: loss scalar + perplexity ----------------
__global__ __launch_bounds__(256) void finalize_kernel(
    const int* __restrict__ hist, const float* __restrict__ loss_acc,
    float* __restrict__ out, int n_rows, int q_count) {
    __shared__ float wsum[4];
    int t = threadIdx.x;
    float invN = 1.f / (float)n_rows;
    float hsum = 0.f;
    for (int k = t; k < KCB; k += 256) {
        float p = (float)hist[k] * invN;
        hsum += p * logf(p + 1e-10f);
    }
#pragma unroll
    for (int off = 32; off > 0; off >>= 1) hsum += __shfl_xor(hsum, off);
    if ((t & 63) == 0) wsum[t >> 6] = hsum;
    __syncthreads();
    if (t == 0) {
        float H = -(wsum[0] + wsum[1] + wsum[2] + wsum[3]);
        out[0] = loss_acc[0] * (1.25f / (float)q_count);  // q_loss + 0.25*e_loss
        out[1 + q_count] = expf(H);
    }
}

extern "C" void kernel_launch(void* const* d_in, const int* in_sizes, int n_in,
                              void* d_out, int out_size, void* d_ws, size_t ws_size,
                              hipStream_t stream) {
    const float* X = (const float*)d_in[0];
    const float* CB = (const float*)d_in[1];
    char* ob = (char*)d_out;
    char* ws = (char*)d_ws;
    int N = in_sizes[0] / DIM;  // 65536 rows

    hipMemsetAsync(ws + HIST_OFF, 0, 4096 + 64, stream);
    prep<<<2048 + 256, 256, 0, stream>>>(X, CB, ob, ws);

    vq_main<<<N / BM, 256, 73728, stream>>>(ob, CB, ws,
                                            (int*)(ws + HIST_OFF),
                                            (float*)(ws + LOSS_OFF));
    finalize_kernel<<<1, 256, 0, stream>>>((int*)(ws + HIST_OFF),
                                           (float*)(ws + LOSS_OFF),
                                           (float*)d_out, N, N * DIM);
}